// Round 1
// baseline (828.684 us; speedup 1.0000x reference)
//
#include <hip/hip_runtime.h>
#include <hip/hip_bf16.h>

// BasicBlock9: B=16, CIN=CP=64, H=W=64, K1=3 (deform), K2=5, EPS=1e-5
// Pipeline:
//   off1 = conv3x3(x, w_off) + b_off                       (18 ch)
//   s1   = relu(bn1(deform_conv3x3(x, off1, w1)))          (64 ch)
//   s1  += relu(bn3(conv5x5(x, w3)))                       (64 ch)
//   out  = relu(bn2(conv3x3(s1, w2)) + x)                  (64 ch)

#define HWv 4096
#define EPSv 1e-5f

// ---------------- Kernel 1: offset conv 3x3, 64 -> 18 ----------------
__global__ __launch_bounds__(256) void offset_conv_kernel(
    const float* __restrict__ x, const float* __restrict__ w_off,
    const float* __restrict__ b_off, float* __restrict__ off1) {
  const int tid = threadIdx.x;
  const int xq = tid & 63;
  const int ty = tid >> 6;
  const int y = blockIdx.x * 4 + ty;   // gridDim.x = 16
  const int b = blockIdx.y;            // 16
  float acc[18];
#pragma unroll
  for (int co = 0; co < 18; ++co) acc[co] = b_off[co];
  const float* xb = x + (size_t)b * 64 * HWv;
  for (int cin = 0; cin < 64; ++cin) {
    const float* xc = xb + cin * HWv;
#pragma unroll
    for (int ky = 0; ky < 3; ++ky) {
      int yy = y + ky - 1;
      if (yy < 0 || yy > 63) continue;  // wave-uniform (whole wave shares y)
      const float* xr = xc + yy * 64;
#pragma unroll
      for (int kx = 0; kx < 3; ++kx) {
        int xx = xq + kx - 1;
        float v = (xx >= 0 && xx <= 63) ? xr[xx] : 0.f;
        const float* wp = w_off + cin * 9 + ky * 3 + kx;  // + co*576
#pragma unroll
        for (int co = 0; co < 18; ++co) acc[co] += v * wp[co * 576];
      }
    }
  }
  float* op = off1 + ((size_t)b * 18) * HWv + y * 64 + xq;
#pragma unroll
  for (int co = 0; co < 18; ++co) op[co * HWv] = acc[co];
}

// ------------- Kernel 2: deformable conv 3x3 + BN1 + ReLU -> sum1 -------------
#define CHUNK2 16
__global__ __launch_bounds__(256) void deform_bn_relu_kernel(
    const float* __restrict__ x, const float* __restrict__ off1,
    const float* __restrict__ w1,
    const float* __restrict__ g1, const float* __restrict__ b1,
    const float* __restrict__ m1, const float* __restrict__ v1,
    float* __restrict__ sum1) {
  __shared__ __align__(16) float lw[CHUNK2 * 9 * 64];  // [c][kk][co] 36.9 KB
  const int tid = threadIdx.x;
  const int xq = tid & 63;
  const int ty = tid >> 6;
  const int y = blockIdx.x * 4 + ty;
  const int b = blockIdx.y;
  float acc[64];
#pragma unroll
  for (int i = 0; i < 64; ++i) acc[i] = 0.f;
  const float* xb = x + (size_t)b * 64 * HWv;
  const float* ob = off1 + ((size_t)b * 18) * HWv + y * 64 + xq;

  for (int cc = 0; cc < 64 / CHUNK2; ++cc) {
    __syncthreads();
    for (int i = tid; i < CHUNK2 * 9 * 64; i += 256) {
      int co = i & 63;
      int kk = (i >> 6) % 9;
      int c = i / (9 * 64);
      lw[i] = w1[(co * 64 + cc * CHUNK2 + c) * 9 + kk];
    }
    __syncthreads();
#pragma unroll
    for (int kk = 0; kk < 9; ++kk) {
      const int ky = kk / 3, kx = kk % 3;
      float dy = ob[(2 * kk) * HWv];
      float dx = ob[(2 * kk + 1) * HWv];
      float ys = (float)(y - 1 + ky) + dy;
      float xs = (float)(xq - 1 + kx) + dx;
      float y0f = floorf(ys), x0f = floorf(xs);
      float wy1 = ys - y0f, wx1 = xs - x0f;
      float wy0 = 1.f - wy1, wx0 = 1.f - wx1;
      int iy0 = (int)y0f, ix0 = (int)x0f;
      int iy1 = iy0 + 1, ix1 = ix0 + 1;
      float vy0 = (iy0 >= 0 && iy0 <= 63) ? 1.f : 0.f;
      float vy1 = (iy1 >= 0 && iy1 <= 63) ? 1.f : 0.f;
      float vx0 = (ix0 >= 0 && ix0 <= 63) ? 1.f : 0.f;
      float vx1 = (ix1 >= 0 && ix1 <= 63) ? 1.f : 0.f;
      int y0c = min(max(iy0, 0), 63), y1c = min(max(iy1, 0), 63);
      int x0c = min(max(ix0, 0), 63), x1c = min(max(ix1, 0), 63);
      float w00 = wy0 * wx0 * vy0 * vx0;
      float w01 = wy0 * wx1 * vy0 * vx1;
      float w10 = wy1 * wx0 * vy1 * vx0;
      float w11 = wy1 * wx1 * vy1 * vx1;
      int i00 = y0c * 64 + x0c, i01 = y0c * 64 + x1c;
      int i10 = y1c * 64 + x0c, i11 = y1c * 64 + x1c;
      for (int c = 0; c < CHUNK2; ++c) {
        const float* xc = xb + (cc * CHUNK2 + c) * HWv;
        float v = w00 * xc[i00] + w01 * xc[i01] + w10 * xc[i10] + w11 * xc[i11];
        const float4* wrow = (const float4*)(&lw[(c * 9 + kk) * 64]);
#pragma unroll
        for (int q = 0; q < 16; ++q) {
          float4 wv = wrow[q];
          acc[q * 4 + 0] += v * wv.x;
          acc[q * 4 + 1] += v * wv.y;
          acc[q * 4 + 2] += v * wv.z;
          acc[q * 4 + 3] += v * wv.w;
        }
      }
    }
  }
  float* op = sum1 + ((size_t)b * 64) * HWv + y * 64 + xq;
#pragma unroll
  for (int co = 0; co < 64; ++co) {
    float s = g1[co] * rsqrtf(v1[co] + EPSv);
    float r = (acc[co] - m1[co]) * s + b1[co];
    op[co * HWv] = r > 0.f ? r : 0.f;
  }
}

// ------------- Kernel 3: conv 5x5 + BN3 + ReLU, sum1 += (co split in 2) -------------
#define CHUNK3 8
__global__ __launch_bounds__(256) void conv5_bn_relu_add_kernel(
    const float* __restrict__ x, const float* __restrict__ w3,
    const float* __restrict__ g3, const float* __restrict__ b3,
    const float* __restrict__ m3, const float* __restrict__ v3,
    float* __restrict__ sum1) {
  __shared__ __align__(16) float lw[CHUNK3 * 25 * 32];  // [c][kk][co] 25.6 KB
  const int tid = threadIdx.x;
  const int xq = tid & 63;
  const int ty = tid >> 6;
  const int y = blockIdx.x * 4 + ty;
  const int b = blockIdx.y;
  const int half = blockIdx.z;  // 0/1 -> couts [half*32, half*32+32)
  float acc[32];
#pragma unroll
  for (int i = 0; i < 32; ++i) acc[i] = 0.f;
  const float* xb = x + (size_t)b * 64 * HWv;

  for (int cc = 0; cc < 64 / CHUNK3; ++cc) {
    __syncthreads();
    for (int i = tid; i < CHUNK3 * 25 * 32; i += 256) {
      int co = i & 31;
      int kk = (i >> 5) % 25;
      int c = i / (25 * 32);
      lw[i] = w3[((half * 32 + co) * 64 + cc * CHUNK3 + c) * 25 + kk];
    }
    __syncthreads();
    for (int c = 0; c < CHUNK3; ++c) {
      const float* xc = xb + (cc * CHUNK3 + c) * HWv;
#pragma unroll
      for (int ky = 0; ky < 5; ++ky) {
        int yy = y + ky - 2;
        if (yy < 0 || yy > 63) continue;  // wave-uniform
        const float* xr = xc + yy * 64;
#pragma unroll
        for (int kx = 0; kx < 5; ++kx) {
          int xx = xq + kx - 2;
          float v = (xx >= 0 && xx <= 63) ? xr[xx] : 0.f;
          const float4* wrow = (const float4*)(&lw[(c * 25 + ky * 5 + kx) * 32]);
#pragma unroll
          for (int q = 0; q < 8; ++q) {
            float4 wv = wrow[q];
            acc[q * 4 + 0] += v * wv.x;
            acc[q * 4 + 1] += v * wv.y;
            acc[q * 4 + 2] += v * wv.z;
            acc[q * 4 + 3] += v * wv.w;
          }
        }
      }
    }
  }
  float* op = sum1 + ((size_t)b * 64 + half * 32) * HWv + y * 64 + xq;
#pragma unroll
  for (int co = 0; co < 32; ++co) {
    int cog = half * 32 + co;
    float s = g3[cog] * rsqrtf(v3[cog] + EPSv);
    float r = (acc[co] - m3[cog]) * s + b3[cog];
    r = r > 0.f ? r : 0.f;
    op[co * HWv] += r;  // add deform branch result already in sum1
  }
}

// ------------- Kernel 4: conv 3x3 on sum1 + BN2 + residual(x) + ReLU -> out -------------
__global__ __launch_bounds__(256) void conv3_bn_res_relu_kernel(
    const float* __restrict__ sum1, const float* __restrict__ x,
    const float* __restrict__ w2,
    const float* __restrict__ g2, const float* __restrict__ b2,
    const float* __restrict__ m2, const float* __restrict__ v2,
    float* __restrict__ out) {
  __shared__ __align__(16) float lw[CHUNK2 * 9 * 64];  // 36.9 KB
  const int tid = threadIdx.x;
  const int xq = tid & 63;
  const int ty = tid >> 6;
  const int y = blockIdx.x * 4 + ty;
  const int b = blockIdx.y;
  float acc[64];
#pragma unroll
  for (int i = 0; i < 64; ++i) acc[i] = 0.f;
  const float* ib = sum1 + (size_t)b * 64 * HWv;

  for (int cc = 0; cc < 64 / CHUNK2; ++cc) {
    __syncthreads();
    for (int i = tid; i < CHUNK2 * 9 * 64; i += 256) {
      int co = i & 63;
      int kk = (i >> 6) % 9;
      int c = i / (9 * 64);
      lw[i] = w2[(co * 64 + cc * CHUNK2 + c) * 9 + kk];
    }
    __syncthreads();
    for (int c = 0; c < CHUNK2; ++c) {
      const float* xc = ib + (cc * CHUNK2 + c) * HWv;
#pragma unroll
      for (int ky = 0; ky < 3; ++ky) {
        int yy = y + ky - 1;
        if (yy < 0 || yy > 63) continue;  // wave-uniform
        const float* xr = xc + yy * 64;
#pragma unroll
        for (int kx = 0; kx < 3; ++kx) {
          int xx = xq + kx - 1;
          float v = (xx >= 0 && xx <= 63) ? xr[xx] : 0.f;
          const float4* wrow = (const float4*)(&lw[(c * 9 + ky * 3 + kx) * 64]);
#pragma unroll
          for (int q = 0; q < 16; ++q) {
            float4 wv = wrow[q];
            acc[q * 4 + 0] += v * wv.x;
            acc[q * 4 + 1] += v * wv.y;
            acc[q * 4 + 2] += v * wv.z;
            acc[q * 4 + 3] += v * wv.w;
          }
        }
      }
    }
  }
  const float* xres = x + ((size_t)b * 64) * HWv + y * 64 + xq;
  float* op = out + ((size_t)b * 64) * HWv + y * 64 + xq;
#pragma unroll
  for (int co = 0; co < 64; ++co) {
    float s = g2[co] * rsqrtf(v2[co] + EPSv);
    float r = (acc[co] - m2[co]) * s + b2[co] + xres[co * HWv];
    op[co * HWv] = r > 0.f ? r : 0.f;
  }
}

extern "C" void kernel_launch(void* const* d_in, const int* in_sizes, int n_in,
                              void* d_out, int out_size, void* d_ws, size_t ws_size,
                              hipStream_t stream) {
  const float* x     = (const float*)d_in[0];
  const float* w_off = (const float*)d_in[1];
  const float* b_off = (const float*)d_in[2];
  const float* w1    = (const float*)d_in[3];
  const float* g1    = (const float*)d_in[4];
  const float* b1    = (const float*)d_in[5];
  const float* m1    = (const float*)d_in[6];
  const float* v1    = (const float*)d_in[7];
  const float* w3    = (const float*)d_in[8];
  const float* g3    = (const float*)d_in[9];
  const float* b3    = (const float*)d_in[10];
  const float* m3    = (const float*)d_in[11];
  const float* v3    = (const float*)d_in[12];
  const float* w2    = (const float*)d_in[13];
  const float* g2    = (const float*)d_in[14];
  const float* b2    = (const float*)d_in[15];
  const float* m2    = (const float*)d_in[16];
  const float* v2    = (const float*)d_in[17];
  float* out = (float*)d_out;

  float* off1 = (float*)d_ws;                       // 16*18*4096 floats = 4.72 MB
  float* sum1 = off1 + (size_t)16 * 18 * HWv;       // 16*64*4096 floats = 16.8 MB

  dim3 blk(256);
  offset_conv_kernel<<<dim3(16, 16), blk, 0, stream>>>(x, w_off, b_off, off1);
  deform_bn_relu_kernel<<<dim3(16, 16), blk, 0, stream>>>(x, off1, w1, g1, b1, m1, v1, sum1);
  conv5_bn_relu_add_kernel<<<dim3(16, 16, 2), blk, 0, stream>>>(x, w3, g3, b3, m3, v3, sum1);
  conv3_bn_res_relu_kernel<<<dim3(16, 16), blk, 0, stream>>>(sum1, x, w2, g2, b2, m2, v2, out);
}

// Round 2
// 351.599 us; speedup vs baseline: 2.3569x; 2.3569x over previous
//
#include <hip/hip_runtime.h>
#include <hip/hip_bf16.h>

// BasicBlock9: B=16, CIN=CP=64, H=W=64, K1=3 (deform), K2=5, EPS=1e-5
// R2: bf16 MFMA implicit-GEMM for offset-conv / conv5 / conv3.
//     Deform stays direct (next round). Layouts:
//       xT / s1T : [b][y][x][ci64] bf16   (transpose_bf16_kernel)
//       wT       : [kk][co_pad][ci64] bf16 (wprep_kernel)
//     GEMM core: wg = 64co x 128px (2 rows); 4 waves; each wave
//     1 m-tile(32co) x 2 n-tiles(32px) of v_mfma_f32_32x32x16_bf16.

#define HWv 4096
#define EPSv 1e-5f

typedef __attribute__((ext_vector_type(8))) short bf16x8;
typedef __attribute__((ext_vector_type(16))) float f32x16;

__device__ inline ushort f2bf(float f) {
  __hip_bfloat16 h = __float2bfloat16(f);
  return *(ushort*)&h;
}

// ---------------- transpose + convert: [b][ci][y][x] f32 -> [b][y][x][ci] bf16 ----------------
__global__ __launch_bounds__(256) void transpose_bf16_kernel(
    const float* __restrict__ src, ushort* __restrict__ dst) {
  __shared__ float tile[64][65];
  const int y = blockIdx.x, b = blockIdx.y;
  for (int i = threadIdx.x; i < 4096; i += 256) {
    int ci = i >> 6, xx = i & 63;
    tile[ci][xx] = src[(((size_t)b * 64 + ci) * 64 + y) * 64 + xx];
  }
  __syncthreads();
  for (int i = threadIdx.x; i < 2048; i += 256) {
    int xx = i >> 5, cip = (i & 31) * 2;
    ushort2 v;
    v.x = f2bf(tile[cip][xx]);
    v.y = f2bf(tile[cip + 1][xx]);
    *(ushort2*)&dst[(((size_t)b * 64 + y) * 64 + xx) * 64 + cip] = v;
  }
}

// ---------------- weight prep: w[co][ci][kk] f32 -> [kk][co_pad][ci] bf16 ----------------
__global__ __launch_bounds__(256) void wprep_kernel(
    const float* __restrict__ w, ushort* __restrict__ out, int CO, int COP, int KK) {
  int idx = blockIdx.x * 256 + threadIdx.x;
  int total = KK * COP * 64;
  if (idx >= total) return;
  int ci = idx & 63;
  int co = (idx >> 6) % COP;
  int kk = idx / (COP * 64);
  float v = (co < CO) ? w[(co * 64 + ci) * KK + kk] : 0.f;
  out[idx] = f2bf(v);
}

// ---------------- MFMA conv GEMM core ----------------
// KK = (2*PAD+1)^2, MT = #m-tiles (1 -> 32 couts, 2 -> 64 couts).
// AwL: [KK][MT*32][16ci] bf16,  BwL: [2+2*PAD][64+2*PAD][16ci] bf16.
template <int KK, int PAD, int MT>
__device__ inline void conv_gemm(const ushort* __restrict__ wT,
                                 const ushort* __restrict__ xT,
                                 ushort* AwL, ushort* BwL,
                                 int b, int y0, f32x16* acc) {
  constexpr int IN_ROWS = 2 + 2 * PAD;
  constexpr int WCOLS = 64 + 2 * PAD;
  constexpr int KW = 2 * PAD + 1;
  const int tid = threadIdx.x;
  const int w = tid >> 6, lane = tid & 63;
  const int ln = lane & 31, kh = lane >> 5;
  const int NT = (MT == 2) ? 2 : 1;
  const int mh = (MT == 2) ? (w & 1) : 0;
  const int nt0 = (MT == 2) ? (w >> 1) * 2 : w;

#pragma unroll
  for (int t = 0; t < ((MT == 2) ? 2 : 1); ++t)
#pragma unroll
    for (int j = 0; j < 16; ++j) acc[t][j] = 0.f;

  // zero x-pad columns (written once; never overwritten by staging)
  for (int i = tid; i < IN_ROWS * 2 * PAD * 16; i += 256) {
    int r = i / (2 * PAD * 16);
    int rem = i % (2 * PAD * 16);
    int pc = rem >> 4, ci = rem & 15;
    int col = (pc < PAD) ? pc : (WCOLS - 2 * PAD + pc);
    BwL[(r * WCOLS + col) * 16 + ci] = 0;
  }

  const uint4* wT4 = (const uint4*)wT;
  const uint4* xT4 = (const uint4*)xT;
  uint4* Aw4 = (uint4*)AwL;
  uint4* Bw4 = (uint4*)BwL;

  for (int ccb = 0; ccb < 4; ++ccb) {
    __syncthreads();
    // stage weights chunk: [kk][co][16ci]
    for (int i = tid; i < KK * MT * 32 * 2; i += 256)
      Aw4[i] = wT4[(size_t)(i >> 1) * 8 + ccb * 2 + (i & 1)];
    // stage input rows (zero-padded y)
    for (int i = tid; i < IN_ROWS * 128; i += 256) {
      int r = i >> 7, rem = i & 127;
      int xx = rem >> 1, ch = rem & 1;
      int yy = y0 - PAD + r;
      uint4 v = make_uint4(0, 0, 0, 0);
      if (yy >= 0 && yy <= 63)
        v = xT4[((size_t)((b * 64 + yy) * 64 + xx) << 3) + ccb * 2 + ch];
      Bw4[(r * WCOLS + PAD + xx) * 2 + ch] = v;
    }
    __syncthreads();
#pragma unroll
    for (int kk = 0; kk < KK; ++kk) {
      const int ky = kk / KW, kx = kk % KW;
      bf16x8 af = *(const bf16x8*)&AwL[((kk * MT * 32) + mh * 32 + ln) * 16 + kh * 8];
#pragma unroll
      for (int t = 0; t < NT; ++t) {
        int p = (nt0 + t) * 32 + ln;
        int ry = p >> 6, px = p & 63;
        bf16x8 bfr = *(const bf16x8*)&BwL[((ry + ky) * WCOLS + px + kx) * 16 + kh * 8];
        acc[t] = __builtin_amdgcn_mfma_f32_32x32x16_bf16(af, bfr, acc[t], 0, 0, 0);
      }
    }
  }
}

// ---------------- Kernel: offset conv 3x3 (64 -> 18, padded to 32) ----------------
__global__ __launch_bounds__(256) void offset_mfma_kernel(
    const ushort* __restrict__ xT, const ushort* __restrict__ wofft,
    const float* __restrict__ b_off, float* __restrict__ off1) {
  __shared__ __align__(16) ushort Aw[9 * 32 * 16];
  __shared__ __align__(16) ushort Bw[4 * 66 * 16];
  const int y0 = blockIdx.x * 2, b = blockIdx.y;
  f32x16 acc[1];
  conv_gemm<9, 1, 1>(wofft, xT, Aw, Bw, b, y0, acc);
  const int tid = threadIdx.x;
  const int w = tid >> 6, lane = tid & 63;
  const int ln = lane & 31, kh = lane >> 5;
  int p = w * 32 + ln;
  int y = y0 + (p >> 6), px = p & 63;
#pragma unroll
  for (int reg = 0; reg < 16; ++reg) {
    int co = (reg & 3) + 8 * (reg >> 2) + 4 * kh;
    if (co < 18)
      off1[((size_t)(b * 18 + co)) * HWv + y * 64 + px] = acc[0][reg] + b_off[co];
  }
}

// ---------------- Kernel: conv5x5 + BN3 + ReLU, sum1 += ----------------
__global__ __launch_bounds__(256) void conv5_mfma_kernel(
    const ushort* __restrict__ xT, const ushort* __restrict__ w3t,
    const float* __restrict__ g3, const float* __restrict__ b3,
    const float* __restrict__ m3, const float* __restrict__ v3,
    float* __restrict__ sum1) {
  __shared__ __align__(16) ushort Aw[25 * 64 * 16];
  __shared__ __align__(16) ushort Bw[6 * 68 * 16];
  __shared__ float sc[64], bi[64];
  const int tid = threadIdx.x;
  if (tid < 64) {
    float s = g3[tid] * rsqrtf(v3[tid] + EPSv);
    sc[tid] = s;
    bi[tid] = b3[tid] - m3[tid] * s;
  }
  const int y0 = blockIdx.x * 2, b = blockIdx.y;
  f32x16 acc[2];
  conv_gemm<25, 2, 2>(w3t, xT, Aw, Bw, b, y0, acc);
  const int w = tid >> 6, lane = tid & 63;
  const int ln = lane & 31, kh = lane >> 5;
  const int mh = w & 1, nt0 = (w >> 1) * 2;
#pragma unroll
  for (int t = 0; t < 2; ++t) {
    int p = (nt0 + t) * 32 + ln;
    int y = y0 + (p >> 6), px = p & 63;
#pragma unroll
    for (int reg = 0; reg < 16; ++reg) {
      int co = (reg & 3) + 8 * (reg >> 2) + 4 * kh + mh * 32;
      float v = acc[t][reg] * sc[co] + bi[co];
      v = v > 0.f ? v : 0.f;
      size_t o = (((size_t)b * 64 + co) * 64 + y) * 64 + px;
      sum1[o] += v;
    }
  }
}

// ---------------- Kernel: conv3x3 on s1 + BN2 + residual + ReLU -> out ----------------
__global__ __launch_bounds__(256) void conv3_mfma_kernel(
    const ushort* __restrict__ s1T, const ushort* __restrict__ w2t,
    const float* __restrict__ g2, const float* __restrict__ b2,
    const float* __restrict__ m2, const float* __restrict__ v2,
    const float* __restrict__ x, float* __restrict__ out) {
  __shared__ __align__(16) ushort Aw[9 * 64 * 16];
  __shared__ __align__(16) ushort Bw[4 * 66 * 16];
  __shared__ float sc[64], bi[64];
  const int tid = threadIdx.x;
  if (tid < 64) {
    float s = g2[tid] * rsqrtf(v2[tid] + EPSv);
    sc[tid] = s;
    bi[tid] = b2[tid] - m2[tid] * s;
  }
  const int y0 = blockIdx.x * 2, b = blockIdx.y;
  f32x16 acc[2];
  conv_gemm<9, 1, 2>(w2t, s1T, Aw, Bw, b, y0, acc);
  const int w = tid >> 6, lane = tid & 63;
  const int ln = lane & 31, kh = lane >> 5;
  const int mh = w & 1, nt0 = (w >> 1) * 2;
#pragma unroll
  for (int t = 0; t < 2; ++t) {
    int p = (nt0 + t) * 32 + ln;
    int y = y0 + (p >> 6), px = p & 63;
#pragma unroll
    for (int reg = 0; reg < 16; ++reg) {
      int co = (reg & 3) + 8 * (reg >> 2) + 4 * kh + mh * 32;
      size_t o = (((size_t)b * 64 + co) * 64 + y) * 64 + px;
      float v = acc[t][reg] * sc[co] + bi[co] + x[o];
      out[o] = v > 0.f ? v : 0.f;
    }
  }
}

// ------------- deformable conv 3x3 + BN1 + ReLU -> sum1 (direct, unchanged) -------------
#define CHUNK2 16
__global__ __launch_bounds__(256) void deform_bn_relu_kernel(
    const float* __restrict__ x, const float* __restrict__ off1,
    const float* __restrict__ w1,
    const float* __restrict__ g1, const float* __restrict__ b1,
    const float* __restrict__ m1, const float* __restrict__ v1,
    float* __restrict__ sum1) {
  __shared__ __align__(16) float lw[CHUNK2 * 9 * 64];
  const int tid = threadIdx.x;
  const int xq = tid & 63;
  const int ty = tid >> 6;
  const int y = blockIdx.x * 4 + ty;
  const int b = blockIdx.y;
  float acc[64];
#pragma unroll
  for (int i = 0; i < 64; ++i) acc[i] = 0.f;
  const float* xb = x + (size_t)b * 64 * HWv;
  const float* ob = off1 + ((size_t)b * 18) * HWv + y * 64 + xq;

  for (int cc = 0; cc < 64 / CHUNK2; ++cc) {
    __syncthreads();
    for (int i = tid; i < CHUNK2 * 9 * 64; i += 256) {
      int co = i & 63;
      int kk = (i >> 6) % 9;
      int c = i / (9 * 64);
      lw[i] = w1[(co * 64 + cc * CHUNK2 + c) * 9 + kk];
    }
    __syncthreads();
#pragma unroll
    for (int kk = 0; kk < 9; ++kk) {
      const int ky = kk / 3, kx = kk % 3;
      float dy = ob[(2 * kk) * HWv];
      float dx = ob[(2 * kk + 1) * HWv];
      float ys = (float)(y - 1 + ky) + dy;
      float xs = (float)(xq - 1 + kx) + dx;
      float y0f = floorf(ys), x0f = floorf(xs);
      float wy1 = ys - y0f, wx1 = xs - x0f;
      float wy0 = 1.f - wy1, wx0 = 1.f - wx1;
      int iy0 = (int)y0f, ix0 = (int)x0f;
      int iy1 = iy0 + 1, ix1 = ix0 + 1;
      float vy0 = (iy0 >= 0 && iy0 <= 63) ? 1.f : 0.f;
      float vy1 = (iy1 >= 0 && iy1 <= 63) ? 1.f : 0.f;
      float vx0 = (ix0 >= 0 && ix0 <= 63) ? 1.f : 0.f;
      float vx1 = (ix1 >= 0 && ix1 <= 63) ? 1.f : 0.f;
      int y0c = min(max(iy0, 0), 63), y1c = min(max(iy1, 0), 63);
      int x0c = min(max(ix0, 0), 63), x1c = min(max(ix1, 0), 63);
      float w00 = wy0 * wx0 * vy0 * vx0;
      float w01 = wy0 * wx1 * vy0 * vx1;
      float w10 = wy1 * wx0 * vy1 * vx0;
      float w11 = wy1 * wx1 * vy1 * vx1;
      int i00 = y0c * 64 + x0c, i01 = y0c * 64 + x1c;
      int i10 = y1c * 64 + x0c, i11 = y1c * 64 + x1c;
      for (int c = 0; c < CHUNK2; ++c) {
        const float* xc = xb + (cc * CHUNK2 + c) * HWv;
        float v = w00 * xc[i00] + w01 * xc[i01] + w10 * xc[i10] + w11 * xc[i11];
        const float4* wrow = (const float4*)(&lw[(c * 9 + kk) * 64]);
#pragma unroll
        for (int q = 0; q < 16; ++q) {
          float4 wv = wrow[q];
          acc[q * 4 + 0] += v * wv.x;
          acc[q * 4 + 1] += v * wv.y;
          acc[q * 4 + 2] += v * wv.z;
          acc[q * 4 + 3] += v * wv.w;
        }
      }
    }
  }
  float* op = sum1 + ((size_t)b * 64) * HWv + y * 64 + xq;
#pragma unroll
  for (int co = 0; co < 64; ++co) {
    float s = g1[co] * rsqrtf(v1[co] + EPSv);
    float r = (acc[co] - m1[co]) * s + b1[co];
    op[co * HWv] = r > 0.f ? r : 0.f;
  }
}

extern "C" void kernel_launch(void* const* d_in, const int* in_sizes, int n_in,
                              void* d_out, int out_size, void* d_ws, size_t ws_size,
                              hipStream_t stream) {
  const float* x     = (const float*)d_in[0];
  const float* w_off = (const float*)d_in[1];
  const float* b_off = (const float*)d_in[2];
  const float* w1    = (const float*)d_in[3];
  const float* g1    = (const float*)d_in[4];
  const float* b1    = (const float*)d_in[5];
  const float* m1    = (const float*)d_in[6];
  const float* v1    = (const float*)d_in[7];
  const float* w3    = (const float*)d_in[8];
  const float* g3    = (const float*)d_in[9];
  const float* b3    = (const float*)d_in[10];
  const float* m3    = (const float*)d_in[11];
  const float* v3    = (const float*)d_in[12];
  const float* w2    = (const float*)d_in[13];
  const float* g2    = (const float*)d_in[14];
  const float* b2    = (const float*)d_in[15];
  const float* m2    = (const float*)d_in[16];
  const float* v2    = (const float*)d_in[17];
  float* out = (float*)d_out;

  // workspace layout (all 16B-aligned)
  float* off1 = (float*)d_ws;                                   // 16*18*4096 f32   = 4.72 MB
  float* sum1 = off1 + (size_t)16 * 18 * HWv;                   // 16*64*4096 f32   = 16.8 MB
  ushort* xT   = (ushort*)(sum1 + (size_t)16 * 64 * HWv);       // 16*64*64*64 bf16 = 8.39 MB
  ushort* s1T  = xT + (size_t)16 * 64 * HWv;                    // 8.39 MB
  ushort* w3t  = s1T + (size_t)16 * 64 * HWv;                   // 25*64*64 bf16
  ushort* w2t  = w3t + 25 * 64 * 64;                            // 9*64*64 bf16
  ushort* woft = w2t + 9 * 64 * 64;                             // 9*32*64 bf16

  dim3 blk(256);
  // weight prep
  wprep_kernel<<<dim3((25 * 64 * 64 + 255) / 256), blk, 0, stream>>>(w3, w3t, 64, 64, 25);
  wprep_kernel<<<dim3((9 * 64 * 64 + 255) / 256), blk, 0, stream>>>(w2, w2t, 64, 64, 9);
  wprep_kernel<<<dim3((9 * 32 * 64 + 255) / 256), blk, 0, stream>>>(w_off, woft, 18, 32, 9);
  // x -> xT (bf16, [b][y][x][ci])
  transpose_bf16_kernel<<<dim3(64, 16), blk, 0, stream>>>(x, xT);
  // offset conv (MFMA)
  offset_mfma_kernel<<<dim3(32, 16), blk, 0, stream>>>(xT, woft, b_off, off1);
  // deform branch (direct) -> sum1
  deform_bn_relu_kernel<<<dim3(16, 16), blk, 0, stream>>>(x, off1, w1, g1, b1, m1, v1, sum1);
  // conv5 branch (MFMA), sum1 +=
  conv5_mfma_kernel<<<dim3(32, 16), blk, 0, stream>>>(xT, w3t, g3, b3, m3, v3, sum1);
  // sum1 -> s1T
  transpose_bf16_kernel<<<dim3(64, 16), blk, 0, stream>>>(sum1, s1T);
  // final conv (MFMA) + residual -> out
  conv3_mfma_kernel<<<dim3(32, 16), blk, 0, stream>>>(s1T, w2t, g2, b2, m2, v2, x, out);
}

// Round 3
// 242.617 us; speedup vs baseline: 3.4156x; 1.4492x over previous
//
#include <hip/hip_runtime.h>
#include <hip/hip_bf16.h>

// BasicBlock9: B=16, CIN=CP=64, H=W=64, K1=3 (deform), K2=5, EPS=1e-5
// R3: all four convs on MFMA.
//   xT        : [b][y][x][ci64] bf16
//   s1T       : [b][y][x][co64] bf16 (deform writes, conv5 +=, conv3 reads)
//   weights   : [kk][co_pad][ci64] bf16
//   deform    : register-space implicit GEMM — per-lane bilinear gather of its
//               own B-fragment (8 ci of one pixel), no LDS, no barriers.
//   conv core : Bw column stride padded to 24 ushorts (48B) -> 4-way instead
//               of 8-way LDS bank conflicts on ds_read_b128.

#define HWv 4096
#define EPSv 1e-5f

typedef __attribute__((ext_vector_type(8))) short bf16x8;
typedef __attribute__((ext_vector_type(16))) float f32x16;

__device__ inline ushort f2bf(float f) {
  __hip_bfloat16 h = __float2bfloat16(f);
  return *(ushort*)&h;
}
__device__ inline float bf2f(ushort u) {
  unsigned int t = ((unsigned int)u) << 16;
  union { unsigned int i; float f; } c; c.i = t; return c.f;
}

// ---------------- transpose + convert: [b][ci][y][x] f32 -> [b][y][x][ci] bf16 ----------------
__global__ __launch_bounds__(256) void transpose_bf16_kernel(
    const float* __restrict__ src, ushort* __restrict__ dst) {
  __shared__ float tile[64][65];
  const int y = blockIdx.x, b = blockIdx.y;
  for (int i = threadIdx.x; i < 4096; i += 256) {
    int ci = i >> 6, xx = i & 63;
    tile[ci][xx] = src[(((size_t)b * 64 + ci) * 64 + y) * 64 + xx];
  }
  __syncthreads();
  for (int i = threadIdx.x; i < 2048; i += 256) {
    int xx = i >> 5, cip = (i & 31) * 2;
    ushort2 v;
    v.x = f2bf(tile[cip][xx]);
    v.y = f2bf(tile[cip + 1][xx]);
    *(ushort2*)&dst[(((size_t)b * 64 + y) * 64 + xx) * 64 + cip] = v;
  }
}

// ---------------- weight prep: w[co][ci][kk] f32 -> [kk][co_pad][ci] bf16 ----------------
__global__ __launch_bounds__(256) void wprep_kernel(
    const float* __restrict__ w, ushort* __restrict__ out, int CO, int COP, int KK) {
  int idx = blockIdx.x * 256 + threadIdx.x;
  int total = KK * COP * 64;
  if (idx >= total) return;
  int ci = idx & 63;
  int co = (idx >> 6) % COP;
  int kk = idx / (COP * 64);
  float v = (co < CO) ? w[(co * 64 + ci) * KK + kk] : 0.f;
  out[idx] = f2bf(v);
}

// ---------------- MFMA conv GEMM core (LDS-staged, for regular convs) ----------------
// KK = (2*PAD+1)^2, MT = #m-tiles (1 -> 32 couts, 2 -> 64 couts).
// AwL: [KK][MT*32][16ci],  BwL: [2+2*PAD][64+2*PAD][BSTR] (data in first 16).
#define BSTR 24
template <int KK, int PAD, int MT>
__device__ inline void conv_gemm(const ushort* __restrict__ wT,
                                 const ushort* __restrict__ xT,
                                 ushort* AwL, ushort* BwL,
                                 int b, int y0, f32x16* acc) {
  constexpr int IN_ROWS = 2 + 2 * PAD;
  constexpr int WCOLS = 64 + 2 * PAD;
  constexpr int KW = 2 * PAD + 1;
  const int tid = threadIdx.x;
  const int w = tid >> 6, lane = tid & 63;
  const int ln = lane & 31, kh = lane >> 5;
  const int NT = (MT == 2) ? 2 : 1;
  const int mh = (MT == 2) ? (w & 1) : 0;
  const int nt0 = (MT == 2) ? (w >> 1) * 2 : w;

#pragma unroll
  for (int t = 0; t < ((MT == 2) ? 2 : 1); ++t)
#pragma unroll
    for (int j = 0; j < 16; ++j) acc[t][j] = 0.f;

  // zero x-pad columns
  for (int i = tid; i < IN_ROWS * 2 * PAD * 16; i += 256) {
    int r = i / (2 * PAD * 16);
    int rem = i % (2 * PAD * 16);
    int pc = rem >> 4, ci = rem & 15;
    int col = (pc < PAD) ? pc : (WCOLS - 2 * PAD + pc);
    BwL[(r * WCOLS + col) * BSTR + ci] = 0;
  }

  const uint4* wT4 = (const uint4*)wT;
  const uint4* xT4 = (const uint4*)xT;
  uint4* Aw4 = (uint4*)AwL;
  uint4* Bw4 = (uint4*)BwL;

  for (int ccb = 0; ccb < 4; ++ccb) {
    __syncthreads();
    // stage weights chunk: [kk][co][16ci]
    for (int i = tid; i < KK * MT * 32 * 2; i += 256)
      Aw4[i] = wT4[(size_t)(i >> 1) * 8 + ccb * 2 + (i & 1)];
    // stage input rows (zero-padded y)
    for (int i = tid; i < IN_ROWS * 128; i += 256) {
      int r = i >> 7, rem = i & 127;
      int xx = rem >> 1, ch = rem & 1;
      int yy = y0 - PAD + r;
      uint4 v = make_uint4(0, 0, 0, 0);
      if (yy >= 0 && yy <= 63)
        v = xT4[((size_t)((b * 64 + yy) * 64 + xx) << 3) + ccb * 2 + ch];
      Bw4[(r * WCOLS + PAD + xx) * 3 + ch] = v;
    }
    __syncthreads();
#pragma unroll
    for (int kk = 0; kk < KK; ++kk) {
      const int ky = kk / KW, kx = kk % KW;
      bf16x8 af = *(const bf16x8*)&AwL[((kk * MT * 32) + mh * 32 + ln) * 16 + kh * 8];
#pragma unroll
      for (int t = 0; t < NT; ++t) {
        int p = (nt0 + t) * 32 + ln;
        int ry = p >> 6, px = p & 63;
        bf16x8 bfr = *(const bf16x8*)&BwL[((ry + ky) * WCOLS + px + kx) * BSTR + kh * 8];
        acc[t] = __builtin_amdgcn_mfma_f32_32x32x16_bf16(af, bfr, acc[t], 0, 0, 0);
      }
    }
  }
}

// ---------------- Kernel: offset conv 3x3 (64 -> 18, padded to 32) ----------------
__global__ __launch_bounds__(256) void offset_mfma_kernel(
    const ushort* __restrict__ xT, const ushort* __restrict__ wofft,
    const float* __restrict__ b_off, float* __restrict__ off1) {
  __shared__ __align__(16) ushort Aw[9 * 32 * 16];
  __shared__ __align__(16) ushort Bw[4 * 66 * BSTR];
  const int y0 = blockIdx.x * 2, b = blockIdx.y;
  f32x16 acc[1];
  conv_gemm<9, 1, 1>(wofft, xT, Aw, Bw, b, y0, acc);
  const int tid = threadIdx.x;
  const int w = tid >> 6, lane = tid & 63;
  const int ln = lane & 31, kh = lane >> 5;
  int p = w * 32 + ln;
  int y = y0 + (p >> 6), px = p & 63;
#pragma unroll
  for (int reg = 0; reg < 16; ++reg) {
    int co = (reg & 3) + 8 * (reg >> 2) + 4 * kh;
    if (co < 18)
      off1[((size_t)(b * 18 + co)) * HWv + y * 64 + px] = acc[0][reg] + b_off[co];
  }
}

// ---------------- Kernel: deformable conv 3x3 + BN1 + ReLU -> s1T (bf16) ----------------
// Register-space implicit GEMM: no LDS, no barriers. Grid (64, 16), 256 thr.
// Wave w: mh = w&1 (co half), nt = w>>1 (px half). Lane gathers its own
// B-fragment (8 ci of pixel px) via 4 bilinear-corner bf16x8 loads.
__global__ __launch_bounds__(256) void deform_mfma_kernel(
    const ushort* __restrict__ xT, const float* __restrict__ off1,
    const ushort* __restrict__ w1t,
    const float* __restrict__ g1, const float* __restrict__ b1,
    const float* __restrict__ m1, const float* __restrict__ v1,
    ushort* __restrict__ s1T) {
  const int tid = threadIdx.x;
  const int w = tid >> 6, lane = tid & 63;
  const int ln = lane & 31, kh = lane >> 5;
  const int mh = w & 1, nt = w >> 1;
  const int y = blockIdx.x, b = blockIdx.y;
  const int px = nt * 32 + ln;
  f32x16 acc;
#pragma unroll
  for (int j = 0; j < 16; ++j) acc[j] = 0.f;
  const ushort* xb = xT + (size_t)b * 64 * 64 * 64;
  const float* ob = off1 + (size_t)b * 18 * HWv + y * 64 + px;
  const ushort* wbase = w1t + (mh * 32 + ln) * 64 + kh * 8;  // + kk*4096 + ks*16

#pragma unroll
  for (int kk = 0; kk < 9; ++kk) {
    const int ky = kk / 3, kx = kk % 3;
    float dy = ob[(2 * kk) * HWv];
    float dx = ob[(2 * kk + 1) * HWv];
    float ys = (float)(y - 1 + ky) + dy;
    float xs = (float)(px - 1 + kx) + dx;
    float y0f = floorf(ys), x0f = floorf(xs);
    float wy1 = ys - y0f, wx1 = xs - x0f;
    float wy0 = 1.f - wy1, wx0 = 1.f - wx1;
    int iy0 = (int)y0f, ix0 = (int)x0f;
    int iy1 = iy0 + 1, ix1 = ix0 + 1;
    float vy0 = (iy0 >= 0 && iy0 <= 63) ? 1.f : 0.f;
    float vy1 = (iy1 >= 0 && iy1 <= 63) ? 1.f : 0.f;
    float vx0 = (ix0 >= 0 && ix0 <= 63) ? 1.f : 0.f;
    float vx1 = (ix1 >= 0 && ix1 <= 63) ? 1.f : 0.f;
    int y0c = min(max(iy0, 0), 63), y1c = min(max(iy1, 0), 63);
    int x0c = min(max(ix0, 0), 63), x1c = min(max(ix1, 0), 63);
    float w00 = wy0 * wx0 * vy0 * vx0;
    float w01 = wy0 * wx1 * vy0 * vx1;
    float w10 = wy1 * wx0 * vy1 * vx0;
    float w11 = wy1 * wx1 * vy1 * vx1;
    const ushort* p00 = xb + (y0c * 64 + x0c) * 64 + kh * 8;
    const ushort* p01 = xb + (y0c * 64 + x1c) * 64 + kh * 8;
    const ushort* p10 = xb + (y1c * 64 + x0c) * 64 + kh * 8;
    const ushort* p11 = xb + (y1c * 64 + x1c) * 64 + kh * 8;
    const ushort* wk = wbase + kk * 4096;
#pragma unroll
    for (int ks = 0; ks < 4; ++ks) {
      bf16x8 af = *(const bf16x8*)(wk + ks * 16);
      bf16x8 va = *(const bf16x8*)(p00 + ks * 16);
      bf16x8 vb = *(const bf16x8*)(p01 + ks * 16);
      bf16x8 vc = *(const bf16x8*)(p10 + ks * 16);
      bf16x8 vd = *(const bf16x8*)(p11 + ks * 16);
      bf16x8 bfrag;
#pragma unroll
      for (int j = 0; j < 8; ++j) {
        float v = w00 * bf2f((ushort)va[j]) + w01 * bf2f((ushort)vb[j]) +
                  w10 * bf2f((ushort)vc[j]) + w11 * bf2f((ushort)vd[j]);
        bfrag[j] = (short)f2bf(v);
      }
      acc = __builtin_amdgcn_mfma_f32_32x32x16_bf16(af, bfrag, acc, 0, 0, 0);
    }
  }
  ushort* op = s1T + ((size_t)(b * 64 + y) * 64 + px) * 64;
#pragma unroll
  for (int q = 0; q < 4; ++q) {
    int co0 = 8 * q + 4 * kh + mh * 32;
    float vv[4];
#pragma unroll
    for (int r = 0; r < 4; ++r) {
      int co = co0 + r;
      float s = g1[co] * rsqrtf(v1[co] + EPSv);
      float rr = (acc[q * 4 + r] - m1[co]) * s + b1[co];
      vv[r] = rr > 0.f ? rr : 0.f;
    }
    ushort4 st;
    st.x = f2bf(vv[0]); st.y = f2bf(vv[1]); st.z = f2bf(vv[2]); st.w = f2bf(vv[3]);
    *(ushort4*)(op + co0) = st;
  }
}

// ---------------- Kernel: conv5x5 + BN3 + ReLU, s1T += (bf16 RMW) ----------------
__global__ __launch_bounds__(256) void conv5_mfma_kernel(
    const ushort* __restrict__ xT, const ushort* __restrict__ w3t,
    const float* __restrict__ g3, const float* __restrict__ b3,
    const float* __restrict__ m3, const float* __restrict__ v3,
    ushort* __restrict__ s1T) {
  __shared__ __align__(16) ushort Aw[25 * 64 * 16];
  __shared__ __align__(16) ushort Bw[6 * 68 * BSTR];
  __shared__ float sc[64], bi[64];
  const int tid = threadIdx.x;
  if (tid < 64) {
    float s = g3[tid] * rsqrtf(v3[tid] + EPSv);
    sc[tid] = s;
    bi[tid] = b3[tid] - m3[tid] * s;
  }
  const int y0 = blockIdx.x * 2, b = blockIdx.y;
  f32x16 acc[2];
  conv_gemm<25, 2, 2>(w3t, xT, Aw, Bw, b, y0, acc);
  const int w = tid >> 6, lane = tid & 63;
  const int ln = lane & 31, kh = lane >> 5;
  const int mh = w & 1, nt0 = (w >> 1) * 2;
#pragma unroll
  for (int t = 0; t < 2; ++t) {
    int p = (nt0 + t) * 32 + ln;
    int y = y0 + (p >> 6), px = p & 63;
    ushort* op = s1T + ((size_t)(b * 64 + y) * 64 + px) * 64;
#pragma unroll
    for (int q = 0; q < 4; ++q) {
      int co0 = 8 * q + 4 * kh + mh * 32;
      ushort4 prev = *(ushort4*)(op + co0);
      float pv[4] = {bf2f(prev.x), bf2f(prev.y), bf2f(prev.z), bf2f(prev.w)};
      float vv[4];
#pragma unroll
      for (int r = 0; r < 4; ++r) {
        int co = co0 + r;
        float v = acc[t][q * 4 + r] * sc[co] + bi[co];
        v = v > 0.f ? v : 0.f;
        vv[r] = v + pv[r];
      }
      ushort4 st;
      st.x = f2bf(vv[0]); st.y = f2bf(vv[1]); st.z = f2bf(vv[2]); st.w = f2bf(vv[3]);
      *(ushort4*)(op + co0) = st;
    }
  }
}

// ---------------- Kernel: conv3x3 on s1T + BN2 + residual + ReLU -> out ----------------
__global__ __launch_bounds__(256) void conv3_mfma_kernel(
    const ushort* __restrict__ s1T, const ushort* __restrict__ w2t,
    const float* __restrict__ g2, const float* __restrict__ b2,
    const float* __restrict__ m2, const float* __restrict__ v2,
    const float* __restrict__ x, float* __restrict__ out) {
  __shared__ __align__(16) ushort Aw[9 * 64 * 16];
  __shared__ __align__(16) ushort Bw[4 * 66 * BSTR];
  __shared__ float sc[64], bi[64];
  const int tid = threadIdx.x;
  if (tid < 64) {
    float s = g2[tid] * rsqrtf(v2[tid] + EPSv);
    sc[tid] = s;
    bi[tid] = b2[tid] - m2[tid] * s;
  }
  const int y0 = blockIdx.x * 2, b = blockIdx.y;
  f32x16 acc[2];
  conv_gemm<9, 1, 2>(w2t, s1T, Aw, Bw, b, y0, acc);
  const int w = tid >> 6, lane = tid & 63;
  const int ln = lane & 31, kh = lane >> 5;
  const int mh = w & 1, nt0 = (w >> 1) * 2;
#pragma unroll
  for (int t = 0; t < 2; ++t) {
    int p = (nt0 + t) * 32 + ln;
    int y = y0 + (p >> 6), px = p & 63;
#pragma unroll
    for (int reg = 0; reg < 16; ++reg) {
      int co = (reg & 3) + 8 * (reg >> 2) + 4 * kh + mh * 32;
      size_t o = (((size_t)b * 64 + co) * 64 + y) * 64 + px;
      float v = acc[t][reg] * sc[co] + bi[co] + x[o];
      out[o] = v > 0.f ? v : 0.f;
    }
  }
}

extern "C" void kernel_launch(void* const* d_in, const int* in_sizes, int n_in,
                              void* d_out, int out_size, void* d_ws, size_t ws_size,
                              hipStream_t stream) {
  const float* x     = (const float*)d_in[0];
  const float* w_off = (const float*)d_in[1];
  const float* b_off = (const float*)d_in[2];
  const float* w1    = (const float*)d_in[3];
  const float* g1    = (const float*)d_in[4];
  const float* b1    = (const float*)d_in[5];
  const float* m1    = (const float*)d_in[6];
  const float* v1    = (const float*)d_in[7];
  const float* w3    = (const float*)d_in[8];
  const float* g3    = (const float*)d_in[9];
  const float* b3    = (const float*)d_in[10];
  const float* m3    = (const float*)d_in[11];
  const float* v3    = (const float*)d_in[12];
  const float* w2    = (const float*)d_in[13];
  const float* g2    = (const float*)d_in[14];
  const float* b2    = (const float*)d_in[15];
  const float* m2    = (const float*)d_in[16];
  const float* v2    = (const float*)d_in[17];
  float* out = (float*)d_out;

  // workspace layout (16B-aligned)
  float*  off1 = (float*)d_ws;                             // 16*18*4096 f32 = 4.72 MB
  ushort* xT   = (ushort*)(off1 + (size_t)16 * 18 * HWv);  // 8.39 MB
  ushort* s1T  = xT + (size_t)16 * 64 * HWv;               // 8.39 MB
  ushort* w3t  = s1T + (size_t)16 * 64 * HWv;              // 25*64*64
  ushort* w2t  = w3t + 25 * 64 * 64;                       // 9*64*64
  ushort* w1t  = w2t + 9 * 64 * 64;                        // 9*64*64
  ushort* woft = w1t + 9 * 64 * 64;                        // 9*32*64

  dim3 blk(256);
  wprep_kernel<<<dim3((25 * 64 * 64 + 255) / 256), blk, 0, stream>>>(w3, w3t, 64, 64, 25);
  wprep_kernel<<<dim3((9 * 64 * 64 + 255) / 256), blk, 0, stream>>>(w2, w2t, 64, 64, 9);
  wprep_kernel<<<dim3((9 * 64 * 64 + 255) / 256), blk, 0, stream>>>(w1, w1t, 64, 64, 9);
  wprep_kernel<<<dim3((9 * 32 * 64 + 255) / 256), blk, 0, stream>>>(w_off, woft, 18, 32, 9);
  transpose_bf16_kernel<<<dim3(64, 16), blk, 0, stream>>>(x, xT);
  offset_mfma_kernel<<<dim3(32, 16), blk, 0, stream>>>(xT, woft, b_off, off1);
  deform_mfma_kernel<<<dim3(64, 16), blk, 0, stream>>>(xT, off1, w1t, g1, b1, m1, v1, s1T);
  conv5_mfma_kernel<<<dim3(32, 16), blk, 0, stream>>>(xT, w3t, g3, b3, m3, v3, s1T);
  conv3_mfma_kernel<<<dim3(32, 16), blk, 0, stream>>>(s1T, w2t, g2, b2, m2, v2, x, out);
}

// Round 4
// 187.595 us; speedup vs baseline: 4.4174x; 1.2933x over previous
//
#include <hip/hip_runtime.h>
#include <hip/hip_bf16.h>

// BasicBlock9: B=16, CIN=CP=64, H=W=64, K1=3 (deform), K2=5, EPS=1e-5
// R4: deform -> LDS-tile gather MFMA.
//   Block = 2 output rows, 256 thr (4 waves: wave = (row r, px-half nt), 64 co
//   via 2 MFMAs -> no duplicated blend). 6-row x-tile (48 KB) XOR-swizzled
//   (chunk ^= px&7) for conflict-free ds_read_b128; per-kk weight tile
//   double-buffered (2x8 KB), one barrier per kk. Per-lane fast-path predicate;
//   rare out-of-tile lanes fall back to global gather (execz-skipped).

#define HWv 4096
#define EPSv 1e-5f

typedef __attribute__((ext_vector_type(8))) short bf16x8;
typedef __attribute__((ext_vector_type(16))) float f32x16;

__device__ inline ushort f2bf(float f) {
  __hip_bfloat16 h = __float2bfloat16(f);
  return *(ushort*)&h;
}
__device__ inline float bf2f(ushort u) {
  unsigned int t = ((unsigned int)u) << 16;
  union { unsigned int i; float f; } c; c.i = t; return c.f;
}

// ---------------- transpose + convert: [b][ci][y][x] f32 -> [b][y][x][ci] bf16 ----------------
__global__ __launch_bounds__(256) void transpose_bf16_kernel(
    const float* __restrict__ src, ushort* __restrict__ dst) {
  __shared__ float tile[64][65];
  const int y = blockIdx.x, b = blockIdx.y;
  for (int i = threadIdx.x; i < 4096; i += 256) {
    int ci = i >> 6, xx = i & 63;
    tile[ci][xx] = src[(((size_t)b * 64 + ci) * 64 + y) * 64 + xx];
  }
  __syncthreads();
  for (int i = threadIdx.x; i < 2048; i += 256) {
    int xx = i >> 5, cip = (i & 31) * 2;
    ushort2 v;
    v.x = f2bf(tile[cip][xx]);
    v.y = f2bf(tile[cip + 1][xx]);
    *(ushort2*)&dst[(((size_t)b * 64 + y) * 64 + xx) * 64 + cip] = v;
  }
}

// ---------------- weight prep: w[co][ci][kk] f32 -> [kk][co_pad][ci] bf16 ----------------
__global__ __launch_bounds__(256) void wprep_kernel(
    const float* __restrict__ w, ushort* __restrict__ out, int CO, int COP, int KK) {
  int idx = blockIdx.x * 256 + threadIdx.x;
  int total = KK * COP * 64;
  if (idx >= total) return;
  int ci = idx & 63;
  int co = (idx >> 6) % COP;
  int kk = idx / (COP * 64);
  float v = (co < CO) ? w[(co * 64 + ci) * KK + kk] : 0.f;
  out[idx] = f2bf(v);
}

// ---------------- MFMA conv GEMM core (LDS-staged, regular convs) ----------------
#define BSTR 24
template <int KK, int PAD, int MT>
__device__ inline void conv_gemm(const ushort* __restrict__ wT,
                                 const ushort* __restrict__ xT,
                                 ushort* AwL, ushort* BwL,
                                 int b, int y0, f32x16* acc) {
  constexpr int IN_ROWS = 2 + 2 * PAD;
  constexpr int WCOLS = 64 + 2 * PAD;
  constexpr int KW = 2 * PAD + 1;
  const int tid = threadIdx.x;
  const int w = tid >> 6, lane = tid & 63;
  const int ln = lane & 31, kh = lane >> 5;
  const int NT = (MT == 2) ? 2 : 1;
  const int mh = (MT == 2) ? (w & 1) : 0;
  const int nt0 = (MT == 2) ? (w >> 1) * 2 : w;

#pragma unroll
  for (int t = 0; t < ((MT == 2) ? 2 : 1); ++t)
#pragma unroll
    for (int j = 0; j < 16; ++j) acc[t][j] = 0.f;

  for (int i = tid; i < IN_ROWS * 2 * PAD * 16; i += 256) {
    int r = i / (2 * PAD * 16);
    int rem = i % (2 * PAD * 16);
    int pc = rem >> 4, ci = rem & 15;
    int col = (pc < PAD) ? pc : (WCOLS - 2 * PAD + pc);
    BwL[(r * WCOLS + col) * BSTR + ci] = 0;
  }

  const uint4* wT4 = (const uint4*)wT;
  const uint4* xT4 = (const uint4*)xT;
  uint4* Aw4 = (uint4*)AwL;
  uint4* Bw4 = (uint4*)BwL;

  for (int ccb = 0; ccb < 4; ++ccb) {
    __syncthreads();
    for (int i = tid; i < KK * MT * 32 * 2; i += 256)
      Aw4[i] = wT4[(size_t)(i >> 1) * 8 + ccb * 2 + (i & 1)];
    for (int i = tid; i < IN_ROWS * 128; i += 256) {
      int r = i >> 7, rem = i & 127;
      int xx = rem >> 1, ch = rem & 1;
      int yy = y0 - PAD + r;
      uint4 v = make_uint4(0, 0, 0, 0);
      if (yy >= 0 && yy <= 63)
        v = xT4[((size_t)((b * 64 + yy) * 64 + xx) << 3) + ccb * 2 + ch];
      Bw4[(r * WCOLS + PAD + xx) * 3 + ch] = v;
    }
    __syncthreads();
#pragma unroll
    for (int kk = 0; kk < KK; ++kk) {
      const int ky = kk / KW, kx = kk % KW;
      bf16x8 af = *(const bf16x8*)&AwL[((kk * MT * 32) + mh * 32 + ln) * 16 + kh * 8];
#pragma unroll
      for (int t = 0; t < NT; ++t) {
        int p = (nt0 + t) * 32 + ln;
        int ry = p >> 6, px = p & 63;
        bf16x8 bfr = *(const bf16x8*)&BwL[((ry + ky) * WCOLS + px + kx) * BSTR + kh * 8];
        acc[t] = __builtin_amdgcn_mfma_f32_32x32x16_bf16(af, bfr, acc[t], 0, 0, 0);
      }
    }
  }
}

// ---------------- Kernel: offset conv 3x3 (64 -> 18, padded to 32) ----------------
__global__ __launch_bounds__(256) void offset_mfma_kernel(
    const ushort* __restrict__ xT, const ushort* __restrict__ wofft,
    const float* __restrict__ b_off, float* __restrict__ off1) {
  __shared__ __align__(16) ushort Aw[9 * 32 * 16];
  __shared__ __align__(16) ushort Bw[4 * 66 * BSTR];
  const int y0 = blockIdx.x * 2, b = blockIdx.y;
  f32x16 acc[1];
  conv_gemm<9, 1, 1>(wofft, xT, Aw, Bw, b, y0, acc);
  const int tid = threadIdx.x;
  const int w = tid >> 6, lane = tid & 63;
  const int ln = lane & 31, kh = lane >> 5;
  int p = w * 32 + ln;
  int y = y0 + (p >> 6), px = p & 63;
#pragma unroll
  for (int reg = 0; reg < 16; ++reg) {
    int co = (reg & 3) + 8 * (reg >> 2) + 4 * kh;
    if (co < 18)
      off1[((size_t)(b * 18 + co)) * HWv + y * 64 + px] = acc[0][reg] + b_off[co];
  }
}

// ---------------- Kernel: deformable conv 3x3 + BN1 + ReLU -> s1T (bf16) ----------------
// Grid (32, 16), 256 thr. Wave = (r = w>>1, nt = w&1); 32 px x 64 co (2 MFMAs).
__global__ __launch_bounds__(256) void deform_mfma_kernel(
    const ushort* __restrict__ xT, const float* __restrict__ off1,
    const ushort* __restrict__ w1t,
    const float* __restrict__ g1, const float* __restrict__ b1,
    const float* __restrict__ m1, const float* __restrict__ v1,
    ushort* __restrict__ s1T) {
  __shared__ __align__(16) uint4 ldsx[6 * 64 * 8];   // 48 KB, chunk ^= px&7
  __shared__ __align__(16) uint4 ldsw[2 * 64 * 8];   // 16 KB dbuf, chunk ^= co&7
  const int tid = threadIdx.x;
  const int wv = tid >> 6, lane = tid & 63;
  const int ln = lane & 31, kh = lane >> 5;
  const int r = wv >> 1, nt = wv & 1;
  const int y0 = blockIdx.x * 2, b = blockIdx.y;
  const int y = y0 + r, px = nt * 32 + ln;
  const uint4* xT4 = (const uint4*)xT;
  const uint4* wT4 = (const uint4*)w1t;

  // stage 6-row x tile (rows clamp(y0-2 .. y0+3)), swizzled
#pragma unroll
  for (int t = 0; t < 12; ++t) {
    int i = tid + t * 256;
    int tr = i >> 9, rem = i & 511, p = rem >> 3, c = rem & 7;
    int ysrc = min(max(y0 - 2 + tr, 0), 63);
    ldsx[(tr * 64 + p) * 8 + (c ^ (p & 7))] =
        xT4[((size_t)((b * 64 + ysrc) * 64 + p)) * 8 + c];
  }
  // stage weights kk=0 into buf 0
#pragma unroll
  for (int t = 0; t < 2; ++t) {
    int i = tid + t * 256;
    int co = i >> 3, c = i & 7;
    ldsw[co * 8 + (c ^ (co & 7))] = wT4[(size_t)co * 8 + c];
  }

  // offsets for this lane's output pixel
  const float* ob = off1 + ((size_t)b * 18) * HWv + y * 64 + px;
  float dyv[9], dxv[9];
#pragma unroll
  for (int kk = 0; kk < 9; ++kk) {
    dyv[kk] = ob[(2 * kk) * HWv];
    dxv[kk] = ob[(2 * kk + 1) * HWv];
  }
  // fast-path predicate: every VALID corner row lies in [y0-2, y0+3]
  bool fast = true;
#pragma unroll
  for (int kk = 0; kk < 9; ++kk) {
    int iy0 = (int)floorf((float)(y - 1 + kk / 3) + dyv[kk]);
    int iy1 = iy0 + 1;
    bool ok0 = (iy0 < 0) || (iy0 > 63) || (iy0 >= y0 - 2 && iy0 <= y0 + 3);
    bool ok1 = (iy1 < 0) || (iy1 > 63) || (iy1 >= y0 - 2 && iy1 <= y0 + 3);
    fast = fast && ok0 && ok1;
  }

  f32x16 acc0, acc1;
#pragma unroll
  for (int j = 0; j < 16; ++j) { acc0[j] = 0.f; acc1[j] = 0.f; }
  const ushort* xb = xT + (size_t)b * 64 * 64 * 64;

  __syncthreads();

#pragma unroll
  for (int kk = 0; kk < 9; ++kk) {
    // prefetch next kk's weights into the other buffer
    if (kk < 8) {
      int par = (kk + 1) & 1;
#pragma unroll
      for (int t = 0; t < 2; ++t) {
        int i = tid + t * 256;
        int co = i >> 3, c = i & 7;
        ldsw[par * 512 + co * 8 + (c ^ (co & 7))] =
            wT4[(size_t)((kk + 1) * 64 + co) * 8 + c];
      }
    }
    const int ky = kk / 3, kx = kk % 3;
    float ys = (float)(y - 1 + ky) + dyv[kk];
    float xs = (float)(px - 1 + kx) + dxv[kk];
    float y0f = floorf(ys), x0f = floorf(xs);
    float wy1 = ys - y0f, wx1 = xs - x0f;
    float wy0 = 1.f - wy1, wx0 = 1.f - wx1;
    int iy0 = (int)y0f, ix0 = (int)x0f;
    int iy1 = iy0 + 1, ix1 = ix0 + 1;
    float vy0 = (iy0 >= 0 && iy0 <= 63) ? 1.f : 0.f;
    float vy1 = (iy1 >= 0 && iy1 <= 63) ? 1.f : 0.f;
    float vx0 = (ix0 >= 0 && ix0 <= 63) ? 1.f : 0.f;
    float vx1 = (ix1 >= 0 && ix1 <= 63) ? 1.f : 0.f;
    int x0c = min(max(ix0, 0), 63), x1c = min(max(ix1, 0), 63);
    float w00 = wy0 * wx0 * vy0 * vx0;
    float w01 = wy0 * wx1 * vy0 * vx1;
    float w10 = wy1 * wx0 * vy1 * vx0;
    float w11 = wy1 * wx1 * vy1 * vx1;
    int tr0 = min(max(iy0 - (y0 - 2), 0), 5);
    int tr1 = min(max(iy1 - (y0 - 2), 0), 5);

    bf16x8 frag[4];
    // fast gather from LDS tile (safe for all lanes; garbage x 0 when invalid)
#pragma unroll
    for (int ks = 0; ks < 4; ++ks) {
      int c = ks * 2 + kh;
      bf16x8 va = *(const bf16x8*)&ldsx[(tr0 * 64 + x0c) * 8 + (c ^ (x0c & 7))];
      bf16x8 vb = *(const bf16x8*)&ldsx[(tr0 * 64 + x1c) * 8 + (c ^ (x1c & 7))];
      bf16x8 vc = *(const bf16x8*)&ldsx[(tr1 * 64 + x0c) * 8 + (c ^ (x0c & 7))];
      bf16x8 vd = *(const bf16x8*)&ldsx[(tr1 * 64 + x1c) * 8 + (c ^ (x1c & 7))];
      bf16x8 f;
#pragma unroll
      for (int j = 0; j < 8; ++j) {
        float v = w00 * bf2f((ushort)va[j]) + w01 * bf2f((ushort)vb[j]) +
                  w10 * bf2f((ushort)vc[j]) + w11 * bf2f((ushort)vd[j]);
        f[j] = (short)f2bf(v);
      }
      frag[ks] = f;
    }
    // slow path: corner row escaped the tile (rare) -> global gather
    if (!fast) {
      int y0c = min(max(iy0, 0), 63), y1c = min(max(iy1, 0), 63);
      const ushort* p00 = xb + (y0c * 64 + x0c) * 64 + kh * 8;
      const ushort* p01 = xb + (y0c * 64 + x1c) * 64 + kh * 8;
      const ushort* p10 = xb + (y1c * 64 + x0c) * 64 + kh * 8;
      const ushort* p11 = xb + (y1c * 64 + x1c) * 64 + kh * 8;
#pragma unroll
      for (int ks = 0; ks < 4; ++ks) {
        bf16x8 va = *(const bf16x8*)(p00 + ks * 16);
        bf16x8 vb = *(const bf16x8*)(p01 + ks * 16);
        bf16x8 vc = *(const bf16x8*)(p10 + ks * 16);
        bf16x8 vd = *(const bf16x8*)(p11 + ks * 16);
        bf16x8 f;
#pragma unroll
        for (int j = 0; j < 8; ++j) {
          float v = w00 * bf2f((ushort)va[j]) + w01 * bf2f((ushort)vb[j]) +
                    w10 * bf2f((ushort)vc[j]) + w11 * bf2f((ushort)vd[j]);
          f[j] = (short)f2bf(v);
        }
        frag[ks] = f;
      }
    }
    // MFMAs (convergent)
    {
      int par = kk & 1;
#pragma unroll
      for (int ks = 0; ks < 4; ++ks) {
        int c = ks * 2 + kh;
        bf16x8 a0 = *(const bf16x8*)&ldsw[par * 512 + ln * 8 + (c ^ (ln & 7))];
        bf16x8 a1 = *(const bf16x8*)&ldsw[par * 512 + (32 + ln) * 8 + (c ^ (ln & 7))];
        acc0 = __builtin_amdgcn_mfma_f32_32x32x16_bf16(a0, frag[ks], acc0, 0, 0, 0);
        acc1 = __builtin_amdgcn_mfma_f32_32x32x16_bf16(a1, frag[ks], acc1, 0, 0, 0);
      }
    }
    __syncthreads();
  }

  ushort* op = s1T + ((size_t)((b * 64 + y) * 64 + px)) * 64;
#pragma unroll
  for (int q = 0; q < 4; ++q) {
    int co0 = 8 * q + 4 * kh;
    float vv[4];
#pragma unroll
    for (int rr = 0; rr < 4; ++rr) {
      int co = co0 + rr;
      float s = g1[co] * rsqrtf(v1[co] + EPSv);
      float t = (acc0[q * 4 + rr] - m1[co]) * s + b1[co];
      vv[rr] = t > 0.f ? t : 0.f;
    }
    ushort4 st;
    st.x = f2bf(vv[0]); st.y = f2bf(vv[1]); st.z = f2bf(vv[2]); st.w = f2bf(vv[3]);
    *(ushort4*)(op + co0) = st;
#pragma unroll
    for (int rr = 0; rr < 4; ++rr) {
      int co = co0 + 32 + rr;
      float s = g1[co] * rsqrtf(v1[co] + EPSv);
      float t = (acc1[q * 4 + rr] - m1[co]) * s + b1[co];
      vv[rr] = t > 0.f ? t : 0.f;
    }
    st.x = f2bf(vv[0]); st.y = f2bf(vv[1]); st.z = f2bf(vv[2]); st.w = f2bf(vv[3]);
    *(ushort4*)(op + co0 + 32) = st;
  }
}

// ---------------- Kernel: conv5x5 + BN3 + ReLU, s1T += (bf16 RMW) ----------------
__global__ __launch_bounds__(256) void conv5_mfma_kernel(
    const ushort* __restrict__ xT, const ushort* __restrict__ w3t,
    const float* __restrict__ g3, const float* __restrict__ b3,
    const float* __restrict__ m3, const float* __restrict__ v3,
    ushort* __restrict__ s1T) {
  __shared__ __align__(16) ushort Aw[25 * 64 * 16];
  __shared__ __align__(16) ushort Bw[6 * 68 * BSTR];
  __shared__ float sc[64], bi[64];
  const int tid = threadIdx.x;
  if (tid < 64) {
    float s = g3[tid] * rsqrtf(v3[tid] + EPSv);
    sc[tid] = s;
    bi[tid] = b3[tid] - m3[tid] * s;
  }
  const int y0 = blockIdx.x * 2, b = blockIdx.y;
  f32x16 acc[2];
  conv_gemm<25, 2, 2>(w3t, xT, Aw, Bw, b, y0, acc);
  const int w = tid >> 6, lane = tid & 63;
  const int ln = lane & 31, kh = lane >> 5;
  const int mh = w & 1, nt0 = (w >> 1) * 2;
#pragma unroll
  for (int t = 0; t < 2; ++t) {
    int p = (nt0 + t) * 32 + ln;
    int y = y0 + (p >> 6), px = p & 63;
    ushort* op = s1T + ((size_t)((b * 64 + y) * 64 + px)) * 64;
#pragma unroll
    for (int q = 0; q < 4; ++q) {
      int co0 = 8 * q + 4 * kh + mh * 32;
      ushort4 prev = *(ushort4*)(op + co0);
      float pv[4] = {bf2f(prev.x), bf2f(prev.y), bf2f(prev.z), bf2f(prev.w)};
      float vv[4];
#pragma unroll
      for (int rr = 0; rr < 4; ++rr) {
        int co = co0 + rr;
        float v = acc[t][q * 4 + rr] * sc[co] + bi[co];
        v = v > 0.f ? v : 0.f;
        vv[rr] = v + pv[rr];
      }
      ushort4 st;
      st.x = f2bf(vv[0]); st.y = f2bf(vv[1]); st.z = f2bf(vv[2]); st.w = f2bf(vv[3]);
      *(ushort4*)(op + co0) = st;
    }
  }
}

// ---------------- Kernel: conv3x3 on s1T + BN2 + residual + ReLU -> out ----------------
__global__ __launch_bounds__(256) void conv3_mfma_kernel(
    const ushort* __restrict__ s1T, const ushort* __restrict__ w2t,
    const float* __restrict__ g2, const float* __restrict__ b2,
    const float* __restrict__ m2, const float* __restrict__ v2,
    const float* __restrict__ x, float* __restrict__ out) {
  __shared__ __align__(16) ushort Aw[9 * 64 * 16];
  __shared__ __align__(16) ushort Bw[4 * 66 * BSTR];
  __shared__ float sc[64], bi[64];
  const int tid = threadIdx.x;
  if (tid < 64) {
    float s = g2[tid] * rsqrtf(v2[tid] + EPSv);
    sc[tid] = s;
    bi[tid] = b2[tid] - m2[tid] * s;
  }
  const int y0 = blockIdx.x * 2, b = blockIdx.y;
  f32x16 acc[2];
  conv_gemm<9, 1, 2>(w2t, s1T, Aw, Bw, b, y0, acc);
  const int w = tid >> 6, lane = tid & 63;
  const int ln = lane & 31, kh = lane >> 5;
  const int mh = w & 1, nt0 = (w >> 1) * 2;
#pragma unroll
  for (int t = 0; t < 2; ++t) {
    int p = (nt0 + t) * 32 + ln;
    int y = y0 + (p >> 6), px = p & 63;
#pragma unroll
    for (int reg = 0; reg < 16; ++reg) {
      int co = (reg & 3) + 8 * (reg >> 2) + 4 * kh + mh * 32;
      size_t o = (((size_t)b * 64 + co) * 64 + y) * 64 + px;
      float v = acc[t][reg] * sc[co] + bi[co] + x[o];
      out[o] = v > 0.f ? v : 0.f;
    }
  }
}

extern "C" void kernel_launch(void* const* d_in, const int* in_sizes, int n_in,
                              void* d_out, int out_size, void* d_ws, size_t ws_size,
                              hipStream_t stream) {
  const float* x     = (const float*)d_in[0];
  const float* w_off = (const float*)d_in[1];
  const float* b_off = (const float*)d_in[2];
  const float* w1    = (const float*)d_in[3];
  const float* g1    = (const float*)d_in[4];
  const float* b1    = (const float*)d_in[5];
  const float* m1    = (const float*)d_in[6];
  const float* v1    = (const float*)d_in[7];
  const float* w3    = (const float*)d_in[8];
  const float* g3    = (const float*)d_in[9];
  const float* b3    = (const float*)d_in[10];
  const float* m3    = (const float*)d_in[11];
  const float* v3    = (const float*)d_in[12];
  const float* w2    = (const float*)d_in[13];
  const float* g2    = (const float*)d_in[14];
  const float* b2    = (const float*)d_in[15];
  const float* m2    = (const float*)d_in[16];
  const float* v2    = (const float*)d_in[17];
  float* out = (float*)d_out;

  float*  off1 = (float*)d_ws;                             // 4.72 MB
  ushort* xT   = (ushort*)(off1 + (size_t)16 * 18 * HWv);  // 8.39 MB
  ushort* s1T  = xT + (size_t)16 * 64 * HWv;               // 8.39 MB
  ushort* w3t  = s1T + (size_t)16 * 64 * HWv;              // 25*64*64
  ushort* w2t  = w3t + 25 * 64 * 64;                       // 9*64*64
  ushort* w1t  = w2t + 9 * 64 * 64;                        // 9*64*64
  ushort* woft = w1t + 9 * 64 * 64;                        // 9*32*64

  dim3 blk(256);
  wprep_kernel<<<dim3((25 * 64 * 64 + 255) / 256), blk, 0, stream>>>(w3, w3t, 64, 64, 25);
  wprep_kernel<<<dim3((9 * 64 * 64 + 255) / 256), blk, 0, stream>>>(w2, w2t, 64, 64, 9);
  wprep_kernel<<<dim3((9 * 64 * 64 + 255) / 256), blk, 0, stream>>>(w1, w1t, 64, 64, 9);
  wprep_kernel<<<dim3((9 * 32 * 64 + 255) / 256), blk, 0, stream>>>(w_off, woft, 18, 32, 9);
  transpose_bf16_kernel<<<dim3(64, 16), blk, 0, stream>>>(x, xT);
  offset_mfma_kernel<<<dim3(32, 16), blk, 0, stream>>>(xT, woft, b_off, off1);
  deform_mfma_kernel<<<dim3(32, 16), blk, 0, stream>>>(xT, off1, w1t, g1, b1, m1, v1, s1T);
  conv5_mfma_kernel<<<dim3(32, 16), blk, 0, stream>>>(xT, w3t, g3, b3, m3, v3, s1T);
  conv3_mfma_kernel<<<dim3(32, 16), blk, 0, stream>>>(s1T, w2t, g2, b2, m2, v2, x, out);
}

// Round 5
// 172.426 us; speedup vs baseline: 4.8060x; 1.0880x over previous
//
#include <hip/hip_runtime.h>
#include <hip/hip_bf16.h>

// BasicBlock9: B=16, CIN=CP=64, H=W=64, K1=3 (deform), K2=5, EPS=1e-5
// R5: 3 dispatches.
//   prep_kernel  : x->xT transpose/bf16 + all 4 weight preps (one grid)
//   fused_kernel : per 2-row block, stage 6x68 zero-padded swizzled x-tile once;
//                  phase1 offset conv (MFMA) -> LDS stash (off1 buffer gone);
//                  phase2 deform gather from tile; phase3 conv5 from tile;
//                  epilogue BN1/BN3+ReLU+add in regs -> single s1T write.
//                  Weights per-kk double-buffered in shared 16KB ldsw.
//   conv3_kernel : conv3x3(s1T) + BN2 + residual + ReLU -> out (conv_gemm core)

#define HWv 4096
#define EPSv 1e-5f

typedef __attribute__((ext_vector_type(8))) short bf16x8;
typedef __attribute__((ext_vector_type(16))) float f32x16;

__device__ inline ushort f2bf(float f) {
  __hip_bfloat16 h = __float2bfloat16(f);
  return *(ushort*)&h;
}
__device__ inline float bf2f(ushort u) {
  unsigned int t = ((unsigned int)u) << 16;
  union { unsigned int i; float f; } c; c.i = t; return c.f;
}

// ---------------- prep: transpose x + all weight preps ----------------
__global__ __launch_bounds__(256) void prep_kernel(
    const float* __restrict__ x, const float* __restrict__ w3,
    const float* __restrict__ w2, const float* __restrict__ w1,
    const float* __restrict__ w_off,
    ushort* __restrict__ xT, ushort* __restrict__ w3t,
    ushort* __restrict__ w2t, ushort* __restrict__ w1t,
    ushort* __restrict__ woft) {
  __shared__ float tile[64][65];
  const int blk = blockIdx.x;
  if (blk < 1024) {
    const int y = blk & 63, b = blk >> 6;
    for (int i = threadIdx.x; i < 4096; i += 256) {
      int ci = i >> 6, xx = i & 63;
      tile[ci][xx] = x[(((size_t)b * 64 + ci) * 64 + y) * 64 + xx];
    }
    __syncthreads();
    for (int i = threadIdx.x; i < 2048; i += 256) {
      int xx = i >> 5, cip = (i & 31) * 2;
      ushort2 v;
      v.x = f2bf(tile[cip][xx]);
      v.y = f2bf(tile[cip + 1][xx]);
      *(ushort2*)&xT[(((size_t)b * 64 + y) * 64 + xx) * 64 + cip] = v;
    }
    return;
  }
  int idx = (blk - 1024) * 256 + threadIdx.x;
  if (idx < 102400) {  // w3t: [kk25][co64][ci64]
    int ci = idx & 63, co = (idx >> 6) & 63, kk = idx >> 12;
    w3t[idx] = f2bf(w3[(co * 64 + ci) * 25 + kk]);
    return;
  }
  idx -= 102400;
  if (idx < 36864) {  // w2t: [kk9][co64][ci64]
    int ci = idx & 63, co = (idx >> 6) & 63, kk = idx >> 12;
    w2t[idx] = f2bf(w2[(co * 64 + ci) * 9 + kk]);
    return;
  }
  idx -= 36864;
  if (idx < 36864) {  // w1t: [kk9][co64][ci64]
    int ci = idx & 63, co = (idx >> 6) & 63, kk = idx >> 12;
    w1t[idx] = f2bf(w1[(co * 64 + ci) * 9 + kk]);
    return;
  }
  idx -= 36864;
  if (idx < 18432) {  // woft: [kk9][co32][ci64], co>=18 zero
    int ci = idx & 63, co = (idx >> 6) & 31, kk = idx >> 11;
    woft[idx] = f2bf(co < 18 ? w_off[(co * 64 + ci) * 9 + kk] : 0.f);
  }
}

// ---------------- fused: offset conv + deform + conv5 -> s1T ----------------
// Grid (32, 16), 256 thr. Wave w: r = w>>1 (row), nt = w&1 (px half).
__global__ __launch_bounds__(256, 2) void fused_kernel(
    const ushort* __restrict__ xT, const ushort* __restrict__ woft,
    const float* __restrict__ b_off, const ushort* __restrict__ w1t,
    const ushort* __restrict__ w3t,
    const float* __restrict__ g1, const float* __restrict__ b1,
    const float* __restrict__ m1, const float* __restrict__ v1,
    const float* __restrict__ g3, const float* __restrict__ b3,
    const float* __restrict__ m3, const float* __restrict__ v3,
    ushort* __restrict__ s1T) {
  __shared__ __align__(16) uint4 ldsx[6 * 68 * 8];  // 52.2 KB zero-padded tile
  __shared__ __align__(16) uint4 ldsw[2 * 512];     // 16 KB weight dbuf
  __shared__ float stash[2 * 64 * 18];              // 9.2 KB offsets
  __shared__ float bn1s[64], bn1b[64], bn3s[64], bn3b[64];

  const int tid = threadIdx.x;
  const int wv = tid >> 6, lane = tid & 63;
  const int ln = lane & 31, kh = lane >> 5;
  const int r = wv >> 1, nt = wv & 1;
  const int y0 = blockIdx.x * 2, b = blockIdx.y;
  const int y = y0 + r, px = nt * 32 + ln;
  const uint4* xT4 = (const uint4*)xT;
  const uint4* wo4 = (const uint4*)woft;
  const uint4* w14 = (const uint4*)w1t;
  const uint4* w34 = (const uint4*)w3t;

  // BN constants
  if (tid < 64) {
    float s = g1[tid] * rsqrtf(v1[tid] + EPSv);
    bn1s[tid] = s; bn1b[tid] = b1[tid] - m1[tid] * s;
    float s3 = g3[tid] * rsqrtf(v3[tid] + EPSv);
    bn3s[tid] = s3; bn3b[tid] = b3[tid] - m3[tid] * s3;
  }
  // stage x-tile: rows y0-2..y0+3 (clamped content for deform; convs skip
  // invalid rows uniformly), cols 0..67 = x cols -2..65 (OOB cols zeroed)
  for (int i = tid; i < 6 * 68 * 8; i += 256) {
    int tr = i / (68 * 8), rem = i % (68 * 8);
    int col = rem >> 3, c = rem & 7;
    int ysrc = min(max(y0 - 2 + tr, 0), 63);
    int xcol = col - 2;
    uint4 v = make_uint4(0, 0, 0, 0);
    if (xcol >= 0 && xcol <= 63)
      v = xT4[((size_t)((b * 64 + ysrc) * 64 + xcol)) * 8 + c];
    ldsx[(tr * 68 + col) * 8 + (c ^ (col & 7))] = v;
  }
  // stage offset-conv weights kk=0 (32 co -> 256 uint4)
  if (tid < 256) {
    int co = tid >> 3, c = tid & 7;
    ldsw[co * 8 + (c ^ (co & 7))] = wo4[(size_t)co * 8 + c];
  }
  __syncthreads();

  // ---------- phase 1: offset conv 3x3 ----------
  f32x16 acco;
#pragma unroll
  for (int j = 0; j < 16; ++j) acco[j] = 0.f;
#pragma unroll
  for (int kk = 0; kk < 9; ++kk) {
    if (kk < 8) {
      int par = (kk + 1) & 1;
      if (tid < 256) {
        int co = tid >> 3, c = tid & 7;
        ldsw[par * 512 + co * 8 + (c ^ (co & 7))] =
            wo4[(size_t)((kk + 1) * 32 + co) * 8 + c];
      }
    }
    const int ky = kk / 3, kx = kk % 3;
    const int yy = y - 1 + ky;
    if (yy >= 0 && yy <= 63) {  // wave-uniform
      const int tr = yy - (y0 - 2);
      const int col = px + kx + 1;  // (px-1+kx)+2
      const int par = kk & 1;
#pragma unroll
      for (int ks = 0; ks < 4; ++ks) {
        int c = ks * 2 + kh;
        bf16x8 af = *(const bf16x8*)&ldsw[par * 512 + ln * 8 + (c ^ (ln & 7))];
        bf16x8 bf = *(const bf16x8*)&ldsx[(tr * 68 + col) * 8 + (c ^ (col & 7))];
        acco = __builtin_amdgcn_mfma_f32_32x32x16_bf16(af, bf, acco, 0, 0, 0);
      }
    }
    __syncthreads();
  }
  // park offsets in stash (C layout: col=ln -> px, row=co)
#pragma unroll
  for (int reg = 0; reg < 16; ++reg) {
    int co = (reg & 3) + 8 * (reg >> 2) + 4 * kh;
    if (co < 18)
      stash[(r * 64 + px) * 18 + co] = acco[reg] + b_off[co];
  }
  __syncthreads();

  float dyv[9], dxv[9];
#pragma unroll
  for (int kk = 0; kk < 9; ++kk) {
    dyv[kk] = stash[(r * 64 + px) * 18 + 2 * kk];
    dxv[kk] = stash[(r * 64 + px) * 18 + 2 * kk + 1];
  }
  // fast-path predicate: every valid corner row in [y0-2, y0+3]
  bool fast = true;
#pragma unroll
  for (int kk = 0; kk < 9; ++kk) {
    int iy0 = (int)floorf((float)(y - 1 + kk / 3) + dyv[kk]);
    int iy1 = iy0 + 1;
    bool ok0 = (iy0 < 0) || (iy0 > 63) || (iy0 >= y0 - 2 && iy0 <= y0 + 3);
    bool ok1 = (iy1 < 0) || (iy1 > 63) || (iy1 >= y0 - 2 && iy1 <= y0 + 3);
    fast = fast && ok0 && ok1;
  }

  // ---------- phase 2: deformable conv 3x3 ----------
  f32x16 accd0, accd1;
#pragma unroll
  for (int j = 0; j < 16; ++j) { accd0[j] = 0.f; accd1[j] = 0.f; }
  const ushort* xb = xT + (size_t)b * 64 * 64 * 64;

  // stage w1 kk=0
  for (int i = tid; i < 512; i += 256) {
    int co = i >> 3, c = i & 7;
    ldsw[co * 8 + (c ^ (co & 7))] = w14[(size_t)co * 8 + c];
  }
  __syncthreads();

#pragma unroll
  for (int kk = 0; kk < 9; ++kk) {
    if (kk < 8) {
      int par = (kk + 1) & 1;
      for (int i = tid; i < 512; i += 256) {
        int co = i >> 3, c = i & 7;
        ldsw[par * 512 + co * 8 + (c ^ (co & 7))] =
            w14[(size_t)((kk + 1) * 64 + co) * 8 + c];
      }
    }
    const int ky = kk / 3, kx = kk % 3;
    float ys = (float)(y - 1 + ky) + dyv[kk];
    float xs = (float)(px - 1 + kx) + dxv[kk];
    float y0f = floorf(ys), x0f = floorf(xs);
    float wy1 = ys - y0f, wx1 = xs - x0f;
    float wy0 = 1.f - wy1, wx0 = 1.f - wx1;
    int iy0 = (int)y0f, ix0 = (int)x0f;
    int iy1 = iy0 + 1, ix1 = ix0 + 1;
    float vy0 = (iy0 >= 0 && iy0 <= 63) ? 1.f : 0.f;
    float vy1 = (iy1 >= 0 && iy1 <= 63) ? 1.f : 0.f;
    float vx0 = (ix0 >= 0 && ix0 <= 63) ? 1.f : 0.f;
    float vx1 = (ix1 >= 0 && ix1 <= 63) ? 1.f : 0.f;
    int x0c = min(max(ix0, 0), 63), x1c = min(max(ix1, 0), 63);
    float w00 = wy0 * wx0 * vy0 * vx0;
    float w01 = wy0 * wx1 * vy0 * vx1;
    float w10 = wy1 * wx0 * vy1 * vx0;
    float w11 = wy1 * wx1 * vy1 * vx1;
    int tr0 = min(max(iy0 - (y0 - 2), 0), 5);
    int tr1 = min(max(iy1 - (y0 - 2), 0), 5);
    int c0 = x0c + 2, c1 = x1c + 2;  // tile cols

    bf16x8 frag[4];
#pragma unroll
    for (int ks = 0; ks < 4; ++ks) {
      int c = ks * 2 + kh;
      bf16x8 va = *(const bf16x8*)&ldsx[(tr0 * 68 + c0) * 8 + (c ^ (c0 & 7))];
      bf16x8 vb = *(const bf16x8*)&ldsx[(tr0 * 68 + c1) * 8 + (c ^ (c1 & 7))];
      bf16x8 vc = *(const bf16x8*)&ldsx[(tr1 * 68 + c0) * 8 + (c ^ (c0 & 7))];
      bf16x8 vd = *(const bf16x8*)&ldsx[(tr1 * 68 + c1) * 8 + (c ^ (c1 & 7))];
      bf16x8 f;
#pragma unroll
      for (int j = 0; j < 8; ++j) {
        float v = w00 * bf2f((ushort)va[j]) + w01 * bf2f((ushort)vb[j]) +
                  w10 * bf2f((ushort)vc[j]) + w11 * bf2f((ushort)vd[j]);
        f[j] = (short)f2bf(v);
      }
      frag[ks] = f;
    }
    if (!fast) {  // rare: corner row escaped tile -> global gather
      int y0c = min(max(iy0, 0), 63), y1c = min(max(iy1, 0), 63);
      const ushort* p00 = xb + (y0c * 64 + x0c) * 64 + kh * 8;
      const ushort* p01 = xb + (y0c * 64 + x1c) * 64 + kh * 8;
      const ushort* p10 = xb + (y1c * 64 + x0c) * 64 + kh * 8;
      const ushort* p11 = xb + (y1c * 64 + x1c) * 64 + kh * 8;
#pragma unroll
      for (int ks = 0; ks < 4; ++ks) {
        bf16x8 va = *(const bf16x8*)(p00 + ks * 16);
        bf16x8 vb = *(const bf16x8*)(p01 + ks * 16);
        bf16x8 vc = *(const bf16x8*)(p10 + ks * 16);
        bf16x8 vd = *(const bf16x8*)(p11 + ks * 16);
        bf16x8 f;
#pragma unroll
        for (int j = 0; j < 8; ++j) {
          float v = w00 * bf2f((ushort)va[j]) + w01 * bf2f((ushort)vb[j]) +
                    w10 * bf2f((ushort)vc[j]) + w11 * bf2f((ushort)vd[j]);
          f[j] = (short)f2bf(v);
        }
        frag[ks] = f;
      }
    }
    {
      int par = kk & 1;
#pragma unroll
      for (int ks = 0; ks < 4; ++ks) {
        int c = ks * 2 + kh;
        bf16x8 a0 = *(const bf16x8*)&ldsw[par * 512 + ln * 8 + (c ^ (ln & 7))];
        bf16x8 a1 = *(const bf16x8*)&ldsw[par * 512 + (32 + ln) * 8 + (c ^ (ln & 7))];
        accd0 = __builtin_amdgcn_mfma_f32_32x32x16_bf16(a0, frag[ks], accd0, 0, 0, 0);
        accd1 = __builtin_amdgcn_mfma_f32_32x32x16_bf16(a1, frag[ks], accd1, 0, 0, 0);
      }
    }
    __syncthreads();
  }

  // ---------- phase 3: conv 5x5 ----------
  f32x16 acc50, acc51;
#pragma unroll
  for (int j = 0; j < 16; ++j) { acc50[j] = 0.f; acc51[j] = 0.f; }
  for (int i = tid; i < 512; i += 256) {
    int co = i >> 3, c = i & 7;
    ldsw[co * 8 + (c ^ (co & 7))] = w34[(size_t)co * 8 + c];
  }
  __syncthreads();

#pragma unroll
  for (int kk = 0; kk < 25; ++kk) {
    if (kk < 24) {
      int par = (kk + 1) & 1;
      for (int i = tid; i < 512; i += 256) {
        int co = i >> 3, c = i & 7;
        ldsw[par * 512 + co * 8 + (c ^ (co & 7))] =
            w34[(size_t)((kk + 1) * 64 + co) * 8 + c];
      }
    }
    const int ky = kk / 5, kx = kk % 5;
    const int yy = y - 2 + ky;
    if (yy >= 0 && yy <= 63) {  // wave-uniform
      const int tr = r + ky;
      const int col = px + kx;  // (px-2+kx)+2
      const int par = kk & 1;
#pragma unroll
      for (int ks = 0; ks < 4; ++ks) {
        int c = ks * 2 + kh;
        bf16x8 bf = *(const bf16x8*)&ldsx[(tr * 68 + col) * 8 + (c ^ (col & 7))];
        bf16x8 a0 = *(const bf16x8*)&ldsw[par * 512 + ln * 8 + (c ^ (ln & 7))];
        bf16x8 a1 = *(const bf16x8*)&ldsw[par * 512 + (32 + ln) * 8 + (c ^ (ln & 7))];
        acc50 = __builtin_amdgcn_mfma_f32_32x32x16_bf16(a0, bf, acc50, 0, 0, 0);
        acc51 = __builtin_amdgcn_mfma_f32_32x32x16_bf16(a1, bf, acc51, 0, 0, 0);
      }
    }
    __syncthreads();
  }

  // ---------- epilogue: s1 = relu(bn1(deform)) + relu(bn3(conv5)) ----------
  ushort* op = s1T + ((size_t)((b * 64 + y) * 64 + px)) * 64;
#pragma unroll
  for (int q = 0; q < 4; ++q) {
    int co0 = 8 * q + 4 * kh;
    float vv[4];
#pragma unroll
    for (int rr = 0; rr < 4; ++rr) {
      int co = co0 + rr;
      float vd = accd0[q * 4 + rr] * bn1s[co] + bn1b[co];
      vd = vd > 0.f ? vd : 0.f;
      float v5 = acc50[q * 4 + rr] * bn3s[co] + bn3b[co];
      v5 = v5 > 0.f ? v5 : 0.f;
      vv[rr] = vd + v5;
    }
    ushort4 st;
    st.x = f2bf(vv[0]); st.y = f2bf(vv[1]); st.z = f2bf(vv[2]); st.w = f2bf(vv[3]);
    *(ushort4*)(op + co0) = st;
#pragma unroll
    for (int rr = 0; rr < 4; ++rr) {
      int co = co0 + 32 + rr;
      float vd = accd1[q * 4 + rr] * bn1s[co] + bn1b[co];
      vd = vd > 0.f ? vd : 0.f;
      float v5 = acc51[q * 4 + rr] * bn3s[co] + bn3b[co];
      v5 = v5 > 0.f ? v5 : 0.f;
      vv[rr] = vd + v5;
    }
    st.x = f2bf(vv[0]); st.y = f2bf(vv[1]); st.z = f2bf(vv[2]); st.w = f2bf(vv[3]);
    *(ushort4*)(op + co0 + 32) = st;
  }
}

// ---------------- conv3x3 on s1T + BN2 + residual + ReLU -> out ----------------
#define BSTR 24
__global__ __launch_bounds__(256) void conv3_mfma_kernel(
    const ushort* __restrict__ s1T, const ushort* __restrict__ w2t,
    const float* __restrict__ g2, const float* __restrict__ b2,
    const float* __restrict__ m2, const float* __restrict__ v2,
    const float* __restrict__ x, float* __restrict__ out) {
  __shared__ __align__(16) ushort Aw[9 * 64 * 16];
  __shared__ __align__(16) ushort Bw[4 * 66 * BSTR];
  __shared__ float sc[64], bi[64];
  const int tid = threadIdx.x;
  if (tid < 64) {
    float s = g2[tid] * rsqrtf(v2[tid] + EPSv);
    sc[tid] = s;
    bi[tid] = b2[tid] - m2[tid] * s;
  }
  const int y0 = blockIdx.x * 2, b = blockIdx.y;
  const int w = tid >> 6, lane = tid & 63;
  const int ln = lane & 31, kh = lane >> 5;
  const int mh = w & 1, nt0 = (w >> 1) * 2;
  f32x16 acc[2];
#pragma unroll
  for (int t = 0; t < 2; ++t)
#pragma unroll
    for (int j = 0; j < 16; ++j) acc[t][j] = 0.f;

  for (int i = tid; i < 4 * 2 * 16; i += 256) {
    int rr = i / 32, rem = i % 32;
    int pc = rem >> 4, ci = rem & 15;
    int col = (pc < 1) ? 0 : 65;
    Bw[(rr * 66 + col) * BSTR + ci] = 0;
  }
  const uint4* wT4 = (const uint4*)w2t;
  const uint4* xT4 = (const uint4*)s1T;
  uint4* Aw4 = (uint4*)Aw;
  uint4* Bw4 = (uint4*)Bw;

  for (int ccb = 0; ccb < 4; ++ccb) {
    __syncthreads();
    for (int i = tid; i < 9 * 64 * 2; i += 256)
      Aw4[i] = wT4[(size_t)(i >> 1) * 8 + ccb * 2 + (i & 1)];
    for (int i = tid; i < 4 * 128; i += 256) {
      int rr = i >> 7, rem = i & 127;
      int xx = rem >> 1, ch = rem & 1;
      int yy = y0 - 1 + rr;
      uint4 v = make_uint4(0, 0, 0, 0);
      if (yy >= 0 && yy <= 63)
        v = xT4[((size_t)((b * 64 + yy) * 64 + xx) << 3) + ccb * 2 + ch];
      Bw4[(rr * 66 + 1 + xx) * 3 + ch] = v;
    }
    __syncthreads();
#pragma unroll
    for (int kk = 0; kk < 9; ++kk) {
      const int ky = kk / 3, kx = kk % 3;
      bf16x8 af = *(const bf16x8*)&Aw[((kk * 64) + mh * 32 + ln) * 16 + kh * 8];
#pragma unroll
      for (int t = 0; t < 2; ++t) {
        int p = (nt0 + t) * 32 + ln;
        int ry = p >> 6, px = p & 63;
        bf16x8 bfr = *(const bf16x8*)&Bw[((ry + ky) * 66 + px + kx) * BSTR + kh * 8];
        acc[t] = __builtin_amdgcn_mfma_f32_32x32x16_bf16(af, bfr, acc[t], 0, 0, 0);
      }
    }
  }
#pragma unroll
  for (int t = 0; t < 2; ++t) {
    int p = (nt0 + t) * 32 + ln;
    int y = y0 + (p >> 6), px = p & 63;
#pragma unroll
    for (int reg = 0; reg < 16; ++reg) {
      int co = (reg & 3) + 8 * (reg >> 2) + 4 * kh + mh * 32;
      size_t o = (((size_t)b * 64 + co) * 64 + y) * 64 + px;
      float v = acc[t][reg] * sc[co] + bi[co] + x[o];
      out[o] = v > 0.f ? v : 0.f;
    }
  }
}

extern "C" void kernel_launch(void* const* d_in, const int* in_sizes, int n_in,
                              void* d_out, int out_size, void* d_ws, size_t ws_size,
                              hipStream_t stream) {
  const float* x     = (const float*)d_in[0];
  const float* w_off = (const float*)d_in[1];
  const float* b_off = (const float*)d_in[2];
  const float* w1    = (const float*)d_in[3];
  const float* g1    = (const float*)d_in[4];
  const float* b1    = (const float*)d_in[5];
  const float* m1    = (const float*)d_in[6];
  const float* v1    = (const float*)d_in[7];
  const float* w3    = (const float*)d_in[8];
  const float* g3    = (const float*)d_in[9];
  const float* b3    = (const float*)d_in[10];
  const float* m3    = (const float*)d_in[11];
  const float* v3    = (const float*)d_in[12];
  const float* w2    = (const float*)d_in[13];
  const float* g2    = (const float*)d_in[14];
  const float* b2    = (const float*)d_in[15];
  const float* m2    = (const float*)d_in[16];
  const float* v2    = (const float*)d_in[17];
  float* out = (float*)d_out;

  ushort* xT   = (ushort*)d_ws;                  // 16*64*4096 bf16 = 8.39 MB
  ushort* s1T  = xT + (size_t)16 * 64 * HWv;     // 8.39 MB
  ushort* w3t  = s1T + (size_t)16 * 64 * HWv;    // 25*64*64
  ushort* w2t  = w3t + 25 * 64 * 64;             // 9*64*64
  ushort* w1t  = w2t + 9 * 64 * 64;              // 9*64*64
  ushort* woft = w1t + 9 * 64 * 64;              // 9*32*64

  dim3 blk(256);
  prep_kernel<<<dim3(1024 + 760), blk, 0, stream>>>(x, w3, w2, w1, w_off,
                                                    xT, w3t, w2t, w1t, woft);
  fused_kernel<<<dim3(32, 16), blk, 0, stream>>>(xT, woft, b_off, w1t, w3t,
                                                 g1, b1, m1, v1, g3, b3, m3, v3,
                                                 s1T);
  conv3_mfma_kernel<<<dim3(32, 16), blk, 0, stream>>>(s1T, w2t, g2, b2, m2, v2,
                                                      x, out);
}